// Round 3
// baseline (252.258 us; speedup 1.0000x reference)
//
#include <hip/hip_runtime.h>
#include <hip/hip_bf16.h>
#include <cmath>

// Problem constants
#define B_SZ 8
#define L_SZ 2048
#define D_SZ 1024
#define CH 341
#define CP 384               // padded channel dim (24 x 16)
#define LCONV 2046           // L - KERNEL + 1
#define NSEG 512
#define KDIM 3072            // 3 * 1024 folded conv K
#define KSTEPS 48            // KDIM / 64

#define POOLED_N (B_SZ * NSEG * D_SZ)

typedef _Float16 f16x8 __attribute__((ext_vector_type(8)));
typedef float f32x4 __attribute__((ext_vector_type(4)));

__device__ __forceinline__ void gl_lds16(const void* g, void* l) {
    __builtin_amdgcn_global_load_lds(
        (const __attribute__((address_space(1))) unsigned int*)g,
        (__attribute__((address_space(3))) unsigned int*)l, 16, 0, 0);
}

// ---------------------------------------------------------------------------
// Convert hidden fp32 -> fp16 (single copy; fixup kernel guarantees sign
// correctness of thresholded logits, so one fp16 pass suffices)
// ---------------------------------------------------------------------------
__global__ __launch_bounds__(256) void convert_hidden_kernel(
        const float* __restrict__ hidden, _Float16* __restrict__ hid16) {
    size_t idx = (size_t)blockIdx.x * 256 + threadIdx.x;   // 8 elems / thread
    float4 v0 = ((const float4*)hidden)[idx * 2];
    float4 v1 = ((const float4*)hidden)[idx * 2 + 1];
    f16x8 o;
    o[0] = (_Float16)v0.x; o[1] = (_Float16)v0.y;
    o[2] = (_Float16)v0.z; o[3] = (_Float16)v0.w;
    o[4] = (_Float16)v1.x; o[5] = (_Float16)v1.y;
    o[6] = (_Float16)v1.z; o[7] = (_Float16)v1.w;
    ((f16x8*)hid16)[idx] = o;
}

// ---------------------------------------------------------------------------
// Convert w1 (Ch,D,K) -> bfrag in EXACT MFMA B-fragment order:
//   flat f16 index fo = (((tt*48 + s)*2 + kc)*64 + lane)*8 + j
//   content: channel c = tt*16 + (lane&15)
//            k         = s*64 + kc*32 + ((lane>>4)<<3) + j   (k' = kk*1024+d)
// so a wave's per-step B fragment is one contiguous 1 KB global_load_dwordx4.
// c padded to 384 with zeros. Also init logits to b2.
// ---------------------------------------------------------------------------
__global__ __launch_bounds__(256) void convert_w1_kernel(
        const float* __restrict__ w1, const float* __restrict__ b2,
        _Float16* __restrict__ bfrag, float* __restrict__ logits) {
    int idx = blockIdx.x * 256 + threadIdx.x;   // < 384*3072
    int j = idx & 7;
    int lane = (idx >> 3) & 63;
    int kc = (idx >> 9) & 1;
    int rest = idx >> 10;
    int s = rest % KSTEPS;
    int tt = rest / KSTEPS;
    int c = tt * 16 + (lane & 15);
    int k = s * 64 + kc * 32 + ((lane >> 4) << 3) + j;
    int kk = k >> 10, d = k & 1023;
    float v = (c < CH) ? w1[((size_t)c * 1024 + d) * 3 + kk] : 0.0f;
    bfrag[idx] = (_Float16)v;
    if (idx < B_SZ * LCONV) logits[idx] = b2[0];
}

// ---------------------------------------------------------------------------
// fp16 MFMA conv GEMM, B-in-registers, fine-grained M split for occupancy.
// Per batch: M=2046(l) x N=384(c) x K=3072.  A[l][k'] = hid16_flat[l*1024+k']
// (folded conv = shifted-row view, linear K walk).
// Tile 32 l x 192 c, BK=64, 4 waves (1x4), wave-tile 32x48 (2x3 of 16x16x32)
// -> 12 MFMAs per step per wave.
// B panel (2.25 MB) is L2-resident, loaded per step straight into registers
// from fragment-ordered bfrag (coalesced 1 KB loads), prefetched ONE STEP
// AHEAD (T14 issue-early / consume-next-iter).
// A (4 KB/step) LDS-staged via gl_lds16, double-buffered (8 KB total).
// Grid (2,64,8) = 1024 blocks = 4 blocks/CU = 16 waves/CU: three sibling
// blocks cover each block's per-step vmcnt(0)+barrier drain (the R2
// bottleneck: 2 blocks/CU gave only one coverer -> MfmaUtil 26%).
// Fused epilogue: relu(h+b1)*w2 reduced over c, atomicAdd into logits.
// ---------------------------------------------------------------------------
#define LDS_BUF 4096         // byte offset between the two A buffers

__global__ __launch_bounds__(256, 4) void conv_mfma_kernel(
        const _Float16* __restrict__ hid16, const _Float16* __restrict__ bfrag,
        const float* __restrict__ b1, const float* __restrict__ w2,
        float* __restrict__ logits) {
    const int nt = blockIdx.x;           // 0..1
    const int mt = blockIdx.y;           // 0..63
    const int b  = blockIdx.z;
    const int l0 = mt * 32;
    const int n0 = nt * 192;
    const int tid = threadIdx.x;
    const int wave = tid >> 6, lane = tid & 63;
    const int wn = wave;                 // 1x4 wave grid: wave = channel strip
    const int quad = lane >> 4, l16 = lane & 15;

    __shared__ __align__(16) char lds[2 * LDS_BUF];   // 8 KB: 2 x A 4K

    const _Float16* hb = hid16 + (size_t)b * L_SZ * D_SZ;

    // A staging source pointer: 256 entries (2 kc x 128), 1 per thread.
    // entry e (within kc): ii=e>>6, m=ii*16+(e&15), koff=((e>>4)&3)*8
    const _Float16* pa;
    {
        int kc = tid >> 7, e = tid & 127;
        int m = ((e >> 6) << 4) + (e & 15);
        int koff = ((e >> 4) & 3) * 8;
        int l = l0 + m; if (l > LCONV - 1) l = LCONV - 1;
        pa = hb + (size_t)l * 1024 + kc * 32 + koff;
    }

    // B fragment pointers: one per jj, advancing 128 f16x8-units (2 KB) / step.
    // Fragment (tt, s, kc) lives at f16x8-unit index ((tt*48+s)*2+kc)*64 + lane.
    const f16x8* bp = (const f16x8*)bfrag;
    const f16x8* bptr[3];
    #pragma unroll
    for (int jj = 0; jj < 3; ++jj) {
        int tt = nt * 12 + wn * 3 + jj;
        bptr[jj] = bp + (size_t)tt * (KSTEPS * 2 * 64) + lane;
    }

    f32x4 acc[2][3] = {};
    f16x8 bc[3][2], bn[3][2];

    // ---- prologue: B step 0 into regs, A step 0 into buffer 0 ----
    #pragma unroll
    for (int jj = 0; jj < 3; ++jj)
        #pragma unroll
        for (int kc = 0; kc < 2; ++kc)
            bc[jj][kc] = bptr[jj][kc * 64];
    #pragma unroll
    for (int jj = 0; jj < 3; ++jj) bptr[jj] += 128;
    gl_lds16(pa, lds + tid * 16);
    pa += 64;
    __syncthreads();          // buffer 0 + bc ready

    int cur = 0;
    for (int s = 0; s < KSTEPS - 1; ++s) {
        const int nxt = cur ^ LDS_BUF;
        // prefetch B step s+1 into regs (consumed next iter)
        #pragma unroll
        for (int jj = 0; jj < 3; ++jj)
            #pragma unroll
            for (int kc = 0; kc < 2; ++kc)
                bn[jj][kc] = bptr[jj][kc * 64];
        #pragma unroll
        for (int jj = 0; jj < 3; ++jj) bptr[jj] += 128;
        // prefetch A step s+1 into other LDS buffer
        gl_lds16(pa, lds + nxt + tid * 16);
        pa += 64;

        // compute step s from cur + bc
        #pragma unroll
        for (int kc = 0; kc < 2; ++kc) {
            f16x8 a[2];
            #pragma unroll
            for (int ii = 0; ii < 2; ++ii)
                a[ii] = *(const f16x8*)(lds + cur + (kc * 128 + ii * 64 + lane) * 16);
            #pragma unroll
            for (int ii = 0; ii < 2; ++ii)
                #pragma unroll
                for (int jj = 0; jj < 3; ++jj)
                    acc[ii][jj] = __builtin_amdgcn_mfma_f32_16x16x32_f16(
                        a[ii], bc[jj][kc], acc[ii][jj], 0, 0, 0);
        }
        __syncthreads();      // vmcnt(0): A nxt + B s+1 landed; cur reads done
        #pragma unroll
        for (int jj = 0; jj < 3; ++jj)
            #pragma unroll
            for (int kc = 0; kc < 2; ++kc)
                bc[jj][kc] = bn[jj][kc];
        cur = nxt;
    }
    // final step (no prefetch)
    #pragma unroll
    for (int kc = 0; kc < 2; ++kc) {
        f16x8 a[2];
        #pragma unroll
        for (int ii = 0; ii < 2; ++ii)
            a[ii] = *(const f16x8*)(lds + cur + (kc * 128 + ii * 64 + lane) * 16);
        #pragma unroll
        for (int ii = 0; ii < 2; ++ii)
            #pragma unroll
            for (int jj = 0; jj < 3; ++jj)
                acc[ii][jj] = __builtin_amdgcn_mfma_f32_16x16x32_f16(
                    a[ii], bc[jj][kc], acc[ii][jj], 0, 0, 0);
    }
    __syncthreads();          // before reusing lds as reduction scratch

    // --- epilogue: relu(acc + b1)*w2, reduce over c, atomic into logits ---
    float cb1[3], cw2[3];
    #pragma unroll
    for (int jj = 0; jj < 3; ++jj) {
        int ch = n0 + wn * 48 + jj * 16 + l16;
        bool v = ch < CH;
        cb1[jj] = v ? b1[ch] : 0.0f;
        cw2[jj] = v ? w2[ch] : 0.0f;
    }
    float* red = (float*)lds;   // [32][4]
    #pragma unroll
    for (int ii = 0; ii < 2; ++ii)
        #pragma unroll
        for (int r = 0; r < 4; ++r) {
            float P = 0.0f;
            #pragma unroll
            for (int jj = 0; jj < 3; ++jj) {
                float h = acc[ii][jj][r] + cb1[jj];
                if (h > 0.0f) P += h * cw2[jj];
            }
            P += __shfl_xor(P, 1);
            P += __shfl_xor(P, 2);
            P += __shfl_xor(P, 4);
            P += __shfl_xor(P, 8);
            if (l16 == 0)
                red[(ii * 16 + quad * 4 + r) * 4 + wn] = P;
        }
    __syncthreads();
    if (tid < 32) {
        int l = l0 + tid;
        if (l < LCONV)
            atomicAdd(&logits[b * LCONV + l],
                      red[tid * 4] + red[tid * 4 + 1] + red[tid * 4 + 2] + red[tid * 4 + 3]);
    }
}

// ---------------------------------------------------------------------------
// Exact fp32 fixup: any |logit| < 0.02 (>>50 sigma of fp16 GEMM error) gets
// recomputed exactly from hidden/w1 in fp32. Expected flagged: <1 position.
// ---------------------------------------------------------------------------
__global__ __launch_bounds__(256) void fixup_kernel(
        const float* __restrict__ hidden, const float* __restrict__ w1,
        const float* __restrict__ b1, const float* __restrict__ w2,
        const float* __restrict__ b2, float* __restrict__ logits) {
    const int b = blockIdx.y, l0 = blockIdx.x * 64, tid = threadIdx.x;
    __shared__ float hrow[3 * 1024];
    __shared__ float sred[256];
    __shared__ int flags[64];
    __shared__ int nflag;
    if (tid == 0) nflag = 0;
    __syncthreads();
    if (tid < 64) {
        int l = l0 + tid;
        if (l < LCONV) {
            float v = logits[b * LCONV + l];
            if (fabsf(v) < 0.02f) { int k = atomicAdd(&nflag, 1); flags[k] = l; }
        }
    }
    __syncthreads();
    const int nf = nflag;
    for (int fi = 0; fi < nf; ++fi) {
        const int l = flags[fi];
        // rows l..l+2 of hidden are 3072 contiguous floats
        for (int t = tid; t < 3072; t += 256)
            hrow[t] = hidden[((size_t)b * L_SZ + l) * 1024 + t];
        __syncthreads();
        float tot = 0.0f;
        for (int c = tid; c < CH; c += 256) {
            const float* wr = w1 + (size_t)c * 3072;
            float dot = 0.0f;
            for (int d = 0; d < 1024; ++d)
                dot += hrow[d] * wr[d * 3] + hrow[1024 + d] * wr[d * 3 + 1]
                     + hrow[2048 + d] * wr[d * 3 + 2];
            float h = dot + b1[c];
            if (h > 0.0f) tot += h * w2[c];
        }
        sred[tid] = tot; __syncthreads();
        for (int off = 128; off > 0; off >>= 1) {
            if (tid < off) sred[tid] += sred[tid + off];
            __syncthreads();
        }
        if (tid == 0) logits[b * LCONV + l] = sred[0] + b2[0];
        __syncthreads();
    }
}

// ---------------------------------------------------------------------------
// Boundary scan: hard bits, segment starts, per-token segment ids,
// short_mask, scalar outputs.
// ---------------------------------------------------------------------------
__global__ void boundary_scan_kernel(const float* __restrict__ logits,
                                     const float* __restrict__ amask,
                                     int* __restrict__ segstart,
                                     int* __restrict__ segid,
                                     float* __restrict__ out_nb,
                                     float* __restrict__ out_tp,
                                     float* __restrict__ short_mask) {
    const int b = blockIdx.x, tid = threadIdx.x;
    __shared__ int sdata[256];
    __shared__ int s_len, s_total;

    int cnt = 0;
    #pragma unroll
    for (int j = 0; j < 8; ++j) {
        int l = tid * 8 + j;
        cnt += (amask[b * L_SZ + l] > 0.5f) ? 1 : 0;
    }
    sdata[tid] = cnt; __syncthreads();
    for (int off = 128; off > 0; off >>= 1) {
        if (tid < off) sdata[tid] += sdata[tid + off];
        __syncthreads();
    }
    if (tid == 0) s_len = sdata[0];
    __syncthreads();
    const int len = s_len;

    int bits[8]; int tsum = 0;
    #pragma unroll
    for (int j = 0; j < 8; ++j) {
        int l = tid * 8 + j;
        int h = 0;
        if (l >= 2 && l < len) h = (logits[b * LCONV + (l - 2)] > 0.0f) ? 1 : 0;
        if (len < L_SZ && l == len - 1) h = 1;
        bits[j] = h; tsum += h;
    }
    __syncthreads();
    sdata[tid] = tsum; __syncthreads();
    for (int off = 1; off < 256; off <<= 1) {
        int v = (tid >= off) ? sdata[tid - off] : 0;
        __syncthreads();
        sdata[tid] += v;
        __syncthreads();
    }
    const int texcl = sdata[tid] - tsum;
    if (tid == 255) s_total = sdata[255];
    __syncthreads();
    const int total = s_total;

    for (int s = tid; s <= NSEG; s += 256)
        segstart[b * (NSEG + 1) + s] = (s == 0) ? 0 : len;
    __syncthreads();
    int run = texcl;
    #pragma unroll
    for (int j = 0; j < 8; ++j) {
        int l = tid * 8 + j;
        int sv = -1;
        if (l < len && run < NSEG) sv = run;
        segid[b * L_SZ + l] = sv;
        if (bits[j]) {
            if (run + 1 <= NSEG) segstart[b * (NSEG + 1) + run + 1] = l + 1;
            run++;
        }
    }

    if (tid == 0) {
        atomicAdd(out_nb, (float)total);
        atomicAdd(out_tp, (float)len);
    }
    for (int s = tid; s < NSEG; s += 256)
        short_mask[b * NSEG + s] = (s < total) ? 1.0f : 0.0f;
}

// ---------------------------------------------------------------------------
// Pool accumulate: 16-token chunks, thread = 4 d over the chunk, atomic flush
// per segment run. Grid (128,8) = 1024 blocks x 256 threads.
// ---------------------------------------------------------------------------
__global__ __launch_bounds__(256) void pool_accum_kernel(
        const float* __restrict__ hidden, const int* __restrict__ segid,
        float* __restrict__ pooled) {
    const int chunk = blockIdx.x, b = blockIdx.y;
    const int tid = threadIdx.x;
    const int d0 = tid * 4;
    const int lbase = chunk * 16;
    const float* hb = hidden + (size_t)b * L_SZ * D_SZ + d0;
    const int* sg = segid + b * L_SZ + lbase;
    float4 acc = make_float4(0.f, 0.f, 0.f, 0.f);
    int cur = -1;
    #pragma unroll
    for (int t = 0; t < 16; ++t) {
        int sid = sg[t];
        if (sid != cur) {
            if (cur >= 0) {
                float* dst = pooled + ((size_t)(b * NSEG + cur)) * D_SZ + d0;
                atomicAdd(dst + 0, acc.x); atomicAdd(dst + 1, acc.y);
                atomicAdd(dst + 2, acc.z); atomicAdd(dst + 3, acc.w);
            }
            acc = make_float4(0.f, 0.f, 0.f, 0.f);
            cur = sid;
        }
        if (sid >= 0) {
            float4 v = *(const float4*)(hb + (size_t)(lbase + t) * D_SZ);
            acc.x += v.x; acc.y += v.y; acc.z += v.z; acc.w += v.w;
        }
    }
    if (cur >= 0) {
        float* dst = pooled + ((size_t)(b * NSEG + cur)) * D_SZ + d0;
        atomicAdd(dst + 0, acc.x); atomicAdd(dst + 1, acc.y);
        atomicAdd(dst + 2, acc.z); atomicAdd(dst + 3, acc.w);
    }
}

// ---------------------------------------------------------------------------
// Pool finalize: divide by count, add sinusoidal PE.
// ---------------------------------------------------------------------------
__global__ __launch_bounds__(256) void pool_final_kernel(
        float* __restrict__ pooled, const int* __restrict__ segstart) {
    const int s = blockIdx.x, b = blockIdx.y, tid = threadIdx.x;
    const int l0 = segstart[b * (NSEG + 1) + s];
    const int l1 = segstart[b * (NSEG + 1) + s + 1];
    const float inv = 1.0f / ((float)(l1 - l0) + 1e-9f);
    const int d0 = tid * 4;
    size_t o = ((size_t)(b * NSEG + s)) * D_SZ + d0;
    float4 v = *(float4*)(pooled + o);
    const float ce = -9.210340371976184f / 512.0f;
    const int i = d0 >> 1;
    const float a0 = (float)s * expf(ce * (float)i);
    const float a1 = (float)s * expf(ce * (float)(i + 1));
    float4 out;
    out.x = v.x * inv + sinf(a0);
    out.y = v.y * inv + cosf(a0);
    out.z = v.z * inv + sinf(a1);
    out.w = v.w * inv + cosf(a1);
    *(float4*)(pooled + o) = out;
}

// ---------------------------------------------------------------------------
extern "C" void kernel_launch(void* const* d_in, const int* in_sizes, int n_in,
                              void* d_out, int out_size, void* d_ws, size_t ws_size,
                              hipStream_t stream) {
    const float* hidden = (const float*)d_in[0];
    const float* amask  = (const float*)d_in[1];
    const float* w1     = (const float*)d_in[2];
    const float* b1     = (const float*)d_in[3];
    const float* w2     = (const float*)d_in[4];
    const float* b2     = (const float*)d_in[5];

    float* out    = (float*)d_out;
    float* pooled = out;
    float* nb     = out + POOLED_N;
    float* tp     = nb + 1;
    float* smask  = out + POOLED_N + 2;

    // zero pooled + scalars (short_mask fully overwritten by scan)
    hipMemsetAsync(d_out, 0, (size_t)(POOLED_N + 2) * sizeof(float), stream);

    const size_t HID_E = (size_t)B_SZ * L_SZ * D_SZ;           // 16,777,216
    const size_t OFF_HID16    = 0;
    const size_t OFF_BPACK    = OFF_HID16 + HID_E * 2;                 // 32 MB
    const size_t OFF_LOGITS   = OFF_BPACK + (size_t)CP * KDIM * 2;     // +2.25 MB
    const size_t OFF_SEGSTART = OFF_LOGITS + (size_t)B_SZ * LCONV * 4;
    const size_t OFF_SEGID    = OFF_SEGSTART + (size_t)B_SZ * (NSEG + 1) * 4;

    _Float16* hid16  = (_Float16*)((char*)d_ws + OFF_HID16);
    _Float16* bfrag  = (_Float16*)((char*)d_ws + OFF_BPACK);
    float*    logits = (float*)((char*)d_ws + OFF_LOGITS);
    int*      segst  = (int*)((char*)d_ws + OFF_SEGSTART);
    int*      segid  = (int*)((char*)d_ws + OFF_SEGID);

    convert_hidden_kernel<<<(int)(HID_E / 8 / 256), 256, 0, stream>>>(hidden, hid16);
    convert_w1_kernel<<<(CP * KDIM) / 256, 256, 0, stream>>>(w1, b2, bfrag, logits);
    conv_mfma_kernel<<<dim3(2, 64, B_SZ), 256, 0, stream>>>(hid16, bfrag, b1, w2, logits);
    fixup_kernel<<<dim3(32, B_SZ), 256, 0, stream>>>(hidden, w1, b1, w2, b2, logits);
    boundary_scan_kernel<<<B_SZ, 256, 0, stream>>>(logits, amask, segst, segid, nb, tp, smask);
    pool_accum_kernel<<<dim3(128, B_SZ), 256, 0, stream>>>(hidden, segid, pooled);
    pool_final_kernel<<<dim3(NSEG, B_SZ), 256, 0, stream>>>(pooled, segst);
}

// Round 4
// 232.788 us; speedup vs baseline: 1.0836x; 1.0836x over previous
//
#include <hip/hip_runtime.h>
#include <hip/hip_bf16.h>
#include <cmath>

// Problem constants
#define B_SZ 8
#define L_SZ 2048
#define D_SZ 1024
#define CH 341
#define CP 384               // padded channel dim (24 x 16)
#define LCONV 2046           // L - KERNEL + 1
#define NSEG 512
#define KDIM 3072            // 3 * 1024 folded conv K
#define KSTEPS 48            // KDIM / 64

#define POOLED_N (B_SZ * NSEG * D_SZ)

typedef _Float16 f16x8 __attribute__((ext_vector_type(8)));
typedef float f32x4 __attribute__((ext_vector_type(4)));

__device__ __forceinline__ void gl_lds16(const void* g, void* l) {
    __builtin_amdgcn_global_load_lds(
        (const __attribute__((address_space(1))) unsigned int*)g,
        (__attribute__((address_space(3))) unsigned int*)l, 16, 0, 0);
}

// ---------------------------------------------------------------------------
// Convert hidden fp32 -> fp16 (single copy; fixup kernel guarantees sign
// correctness of thresholded logits, so one fp16 pass suffices)
// ---------------------------------------------------------------------------
__global__ __launch_bounds__(256) void convert_hidden_kernel(
        const float* __restrict__ hidden, _Float16* __restrict__ hid16) {
    size_t idx = (size_t)blockIdx.x * 256 + threadIdx.x;   // 8 elems / thread
    float4 v0 = ((const float4*)hidden)[idx * 2];
    float4 v1 = ((const float4*)hidden)[idx * 2 + 1];
    f16x8 o;
    o[0] = (_Float16)v0.x; o[1] = (_Float16)v0.y;
    o[2] = (_Float16)v0.z; o[3] = (_Float16)v0.w;
    o[4] = (_Float16)v1.x; o[5] = (_Float16)v1.y;
    o[6] = (_Float16)v1.z; o[7] = (_Float16)v1.w;
    ((f16x8*)hid16)[idx] = o;
}

// ---------------------------------------------------------------------------
// Convert w1 (Ch,D,K) -> bfrag in EXACT MFMA B-fragment order:
//   flat f16 index fo = (((tt*48 + s)*2 + kc)*64 + lane)*8 + j
//   content: channel c = tt*16 + (lane&15)
//            k         = s*64 + kc*32 + ((lane>>4)<<3) + j   (k' = kk*1024+d)
// so a wave's per-step B fragment is one contiguous 1 KB global_load_dwordx4.
// c padded to 384 with zeros. Also init logits to b2.
// ---------------------------------------------------------------------------
__global__ __launch_bounds__(256) void convert_w1_kernel(
        const float* __restrict__ w1, const float* __restrict__ b2,
        _Float16* __restrict__ bfrag, float* __restrict__ logits) {
    int idx = blockIdx.x * 256 + threadIdx.x;   // < 384*3072
    int j = idx & 7;
    int lane = (idx >> 3) & 63;
    int kc = (idx >> 9) & 1;
    int rest = idx >> 10;
    int s = rest % KSTEPS;
    int tt = rest / KSTEPS;
    int c = tt * 16 + (lane & 15);
    int k = s * 64 + kc * 32 + ((lane >> 4) << 3) + j;
    int kk = k >> 10, d = k & 1023;
    float v = (c < CH) ? w1[((size_t)c * 1024 + d) * 3 + kk] : 0.0f;
    bfrag[idx] = (_Float16)v;
    if (idx < B_SZ * LCONV) logits[idx] = b2[0];
}

// ---------------------------------------------------------------------------
// fp16 MFMA conv GEMM, B-in-registers, 3-deep counted-vmcnt pipeline (T3/T4).
// Per batch: M=2046(l) x N=384(c) x K=3072.  A[l][k'] = hid16_flat[l*1024+k']
// (folded conv = shifted-row view, linear K walk).
// Tile 64 l x 192 c (R2's best shape), BK=64, 4 waves (1x4), wave-tile 64x48
// (4x3 of 16x16x32) -> 24 MFMAs per step per wave.
// Per step: 6 B reg loads + 2 A gl_lds = 8 VMEM/thread. Steady state keeps
// TWO batches (16 ops) in flight; s_waitcnt vmcnt(8) retires exactly the
// batch needed. Raw s_barrier (no drain). Issue->wait distance = 2 compute
// phases (~1000 cyc) covers HBM/L2 latency — R2's vmcnt(0)-per-step drain
// (via __syncthreads) was the 57.8 us bottleneck.
// A triple-buffered in LDS (3 x 8 KB); B in 3 rotating named reg sets
// (unroll-by-3 keeps all indices compile-time, rule #20).
// Grid (2,32,8) = 512 blocks = 2 blocks/CU.
// Fused epilogue: relu(h+b1)*w2 reduced over c, atomicAdd into logits.
// ---------------------------------------------------------------------------
#define LDS_BUF 8192         // one A buffer

#define WAITV8() asm volatile("s_waitcnt vmcnt(8)" ::: "memory")
#define WAITV0() asm volatile("s_waitcnt vmcnt(0)" ::: "memory")
#define BAR()    __builtin_amdgcn_s_barrier()

#define LOAD_B(DST) do {                                                    \
    _Pragma("unroll")                                                       \
    for (int jj = 0; jj < 3; ++jj) {                                        \
        DST[jj][0] = bptr[jj][0];                                           \
        DST[jj][1] = bptr[jj][64];                                          \
        bptr[jj] += 128;                                                    \
    } } while (0)

#define ISSUE_A(OFF) do {                                                   \
    gl_lds16(pa0, lds + (OFF) + (wave * 64) * 16);                          \
    gl_lds16(pa1, lds + (OFF) + (256 + wave * 64) * 16);                    \
    pa0 += 64; pa1 += 64; } while (0)

#define COMPUTE(OFF, BSET) do {                                             \
    _Pragma("unroll")                                                       \
    for (int kc = 0; kc < 2; ++kc) {                                        \
        f16x8 a[4];                                                         \
        _Pragma("unroll")                                                   \
        for (int ii = 0; ii < 4; ++ii)                                      \
            a[ii] = *(const f16x8*)(lds + (OFF) + (kc * 256 + ii * 64 + lane) * 16); \
        _Pragma("unroll")                                                   \
        for (int ii = 0; ii < 4; ++ii)                                      \
            _Pragma("unroll")                                               \
            for (int jj = 0; jj < 3; ++jj)                                  \
                acc[ii][jj] = __builtin_amdgcn_mfma_f32_16x16x32_f16(       \
                    a[ii], BSET[jj][kc], acc[ii][jj], 0, 0, 0);             \
    } } while (0)

__global__ __launch_bounds__(256, 2) void conv_mfma_kernel(
        const _Float16* __restrict__ hid16, const _Float16* __restrict__ bfrag,
        const float* __restrict__ b1, const float* __restrict__ w2,
        float* __restrict__ logits) {
    const int nt = blockIdx.x;           // 0..1
    const int mt = blockIdx.y;           // 0..31
    const int b  = blockIdx.z;
    const int l0 = mt * 64;
    const int n0 = nt * 192;
    const int tid = threadIdx.x;
    const int wave = tid >> 6, lane = tid & 63;
    const int wn = wave;                 // 1x4 wave grid: wave = channel strip
    const int quad = lane >> 4, l16 = lane & 15;

    __shared__ __align__(16) char lds[3 * LDS_BUF];   // 24 KB: 3 x A 8K

    const _Float16* hb = hid16 + (size_t)b * L_SZ * D_SZ;

    // A staging source pointers: 512 entries (2 kc x 256), 2 per thread.
    // entry e (within kc): i=e>>6 (row block), m=i*16+(e&15), koff=((e>>4)&3)*8
    const _Float16* pa0;
    const _Float16* pa1;
    {
        int f0 = tid;                    // kc=0 half
        int m0 = ((f0 >> 6) << 4) + (f0 & 15);
        int k0 = ((f0 >> 4) & 3) * 8;
        int l = l0 + m0; if (l > LCONV - 1) l = LCONV - 1;
        pa0 = hb + (size_t)l * 1024 + k0;
        int f1 = tid;                    // kc=1 half
        int m1 = ((f1 >> 6) << 4) + (f1 & 15);
        int k1 = ((f1 >> 4) & 3) * 8;
        l = l0 + m1; if (l > LCONV - 1) l = LCONV - 1;
        pa1 = hb + (size_t)l * 1024 + 32 + k1;
    }

    // B fragment pointers: one per jj, advancing 128 f16x8-units (2 KB) / step.
    // Fragment (tt, s, kc) lives at f16x8-unit index ((tt*48+s)*2+kc)*64 + lane.
    const f16x8* bp = (const f16x8*)bfrag;
    const f16x8* bptr[3];
    #pragma unroll
    for (int jj = 0; jj < 3; ++jj) {
        int tt = nt * 12 + wn * 3 + jj;
        bptr[jj] = bp + (size_t)tt * (KSTEPS * 2 * 64) + lane;
    }

    f32x4 acc[4][3] = {};
    f16x8 B0[3][2], B1[3][2], B2[3][2];

    // ---- prologue: batches 0 and 1 in flight (8 VMEM each) ----
    LOAD_B(B0); ISSUE_A(0);
    LOAD_B(B1); ISSUE_A(LDS_BUF);

    // steps 0..44, unrolled by 3 (buffer/set rotation is compile-time)
    for (int t = 0; t < 15; ++t) {
        WAITV8(); BAR();                 // batch 3t retired; 3t+1 in flight
        LOAD_B(B2); ISSUE_A(2 * LDS_BUF);  // issue batch 3t+2
        COMPUTE(0, B0);                  // compute step 3t

        WAITV8(); BAR();                 // batch 3t+1 retired
        LOAD_B(B0); ISSUE_A(0);          // issue batch 3t+3
        COMPUTE(LDS_BUF, B1);            // compute step 3t+1

        WAITV8(); BAR();                 // batch 3t+2 retired
        LOAD_B(B1); ISSUE_A(LDS_BUF);    // issue batch 3t+4
        COMPUTE(2 * LDS_BUF, B2);        // compute step 3t+2
    }
    // tail: steps 45,46,47 (batches 45,46 in flight; 47 not yet issued)
    WAITV8(); BAR();                     // batch 45 retired
    LOAD_B(B2); ISSUE_A(2 * LDS_BUF);    // issue batch 47
    COMPUTE(0, B0);                      // step 45
    WAITV8(); BAR();                     // batch 46 retired
    COMPUTE(LDS_BUF, B1);                // step 46
    WAITV0(); BAR();                     // batch 47 retired
    COMPUTE(2 * LDS_BUF, B2);            // step 47

    __syncthreads();          // before reusing lds as reduction scratch

    // --- epilogue: relu(acc + b1)*w2, reduce over c, atomic into logits ---
    float cb1[3], cw2[3];
    #pragma unroll
    for (int jj = 0; jj < 3; ++jj) {
        int ch = n0 + wn * 48 + jj * 16 + l16;
        bool v = ch < CH;
        cb1[jj] = v ? b1[ch] : 0.0f;
        cw2[jj] = v ? w2[ch] : 0.0f;
    }
    float* red = (float*)lds;   // [64][4]
    #pragma unroll
    for (int ii = 0; ii < 4; ++ii)
        #pragma unroll
        for (int r = 0; r < 4; ++r) {
            float P = 0.0f;
            #pragma unroll
            for (int jj = 0; jj < 3; ++jj) {
                float h = acc[ii][jj][r] + cb1[jj];
                if (h > 0.0f) P += h * cw2[jj];
            }
            P += __shfl_xor(P, 1);
            P += __shfl_xor(P, 2);
            P += __shfl_xor(P, 4);
            P += __shfl_xor(P, 8);
            if (l16 == 0)
                red[(ii * 16 + quad * 4 + r) * 4 + wn] = P;
        }
    __syncthreads();
    if (tid < 64) {
        int l = l0 + tid;
        if (l < LCONV)
            atomicAdd(&logits[b * LCONV + l],
                      red[tid * 4] + red[tid * 4 + 1] + red[tid * 4 + 2] + red[tid * 4 + 3]);
    }
}

// ---------------------------------------------------------------------------
// Exact fp32 fixup: any |logit| < 0.02 (>>50 sigma of fp16 GEMM error) gets
// recomputed exactly from hidden/w1 in fp32. Expected flagged: <1 position.
// ---------------------------------------------------------------------------
__global__ __launch_bounds__(256) void fixup_kernel(
        const float* __restrict__ hidden, const float* __restrict__ w1,
        const float* __restrict__ b1, const float* __restrict__ w2,
        const float* __restrict__ b2, float* __restrict__ logits) {
    const int b = blockIdx.y, l0 = blockIdx.x * 64, tid = threadIdx.x;
    __shared__ float hrow[3 * 1024];
    __shared__ float sred[256];
    __shared__ int flags[64];
    __shared__ int nflag;
    if (tid == 0) nflag = 0;
    __syncthreads();
    if (tid < 64) {
        int l = l0 + tid;
        if (l < LCONV) {
            float v = logits[b * LCONV + l];
            if (fabsf(v) < 0.02f) { int k = atomicAdd(&nflag, 1); flags[k] = l; }
        }
    }
    __syncthreads();
    const int nf = nflag;
    for (int fi = 0; fi < nf; ++fi) {
        const int l = flags[fi];
        // rows l..l+2 of hidden are 3072 contiguous floats
        for (int t = tid; t < 3072; t += 256)
            hrow[t] = hidden[((size_t)b * L_SZ + l) * 1024 + t];
        __syncthreads();
        float tot = 0.0f;
        for (int c = tid; c < CH; c += 256) {
            const float* wr = w1 + (size_t)c * 3072;
            float dot = 0.0f;
            for (int d = 0; d < 1024; ++d)
                dot += hrow[d] * wr[d * 3] + hrow[1024 + d] * wr[d * 3 + 1]
                     + hrow[2048 + d] * wr[d * 3 + 2];
            float h = dot + b1[c];
            if (h > 0.0f) tot += h * w2[c];
        }
        sred[tid] = tot; __syncthreads();
        for (int off = 128; off > 0; off >>= 1) {
            if (tid < off) sred[tid] += sred[tid + off];
            __syncthreads();
        }
        if (tid == 0) logits[b * LCONV + l] = sred[0] + b2[0];
        __syncthreads();
    }
}

// ---------------------------------------------------------------------------
// Boundary scan: hard bits, segment starts, per-token segment ids,
// short_mask, scalar outputs.
// ---------------------------------------------------------------------------
__global__ void boundary_scan_kernel(const float* __restrict__ logits,
                                     const float* __restrict__ amask,
                                     int* __restrict__ segstart,
                                     int* __restrict__ segid,
                                     float* __restrict__ out_nb,
                                     float* __restrict__ out_tp,
                                     float* __restrict__ short_mask) {
    const int b = blockIdx.x, tid = threadIdx.x;
    __shared__ int sdata[256];
    __shared__ int s_len, s_total;

    int cnt = 0;
    #pragma unroll
    for (int j = 0; j < 8; ++j) {
        int l = tid * 8 + j;
        cnt += (amask[b * L_SZ + l] > 0.5f) ? 1 : 0;
    }
    sdata[tid] = cnt; __syncthreads();
    for (int off = 128; off > 0; off >>= 1) {
        if (tid < off) sdata[tid] += sdata[tid + off];
        __syncthreads();
    }
    if (tid == 0) s_len = sdata[0];
    __syncthreads();
    const int len = s_len;

    int bits[8]; int tsum = 0;
    #pragma unroll
    for (int j = 0; j < 8; ++j) {
        int l = tid * 8 + j;
        int h = 0;
        if (l >= 2 && l < len) h = (logits[b * LCONV + (l - 2)] > 0.0f) ? 1 : 0;
        if (len < L_SZ && l == len - 1) h = 1;
        bits[j] = h; tsum += h;
    }
    __syncthreads();
    sdata[tid] = tsum; __syncthreads();
    for (int off = 1; off < 256; off <<= 1) {
        int v = (tid >= off) ? sdata[tid - off] : 0;
        __syncthreads();
        sdata[tid] += v;
        __syncthreads();
    }
    const int texcl = sdata[tid] - tsum;
    if (tid == 255) s_total = sdata[255];
    __syncthreads();
    const int total = s_total;

    for (int s = tid; s <= NSEG; s += 256)
        segstart[b * (NSEG + 1) + s] = (s == 0) ? 0 : len;
    __syncthreads();
    int run = texcl;
    #pragma unroll
    for (int j = 0; j < 8; ++j) {
        int l = tid * 8 + j;
        int sv = -1;
        if (l < len && run < NSEG) sv = run;
        segid[b * L_SZ + l] = sv;
        if (bits[j]) {
            if (run + 1 <= NSEG) segstart[b * (NSEG + 1) + run + 1] = l + 1;
            run++;
        }
    }

    if (tid == 0) {
        atomicAdd(out_nb, (float)total);
        atomicAdd(out_tp, (float)len);
    }
    for (int s = tid; s < NSEG; s += 256)
        short_mask[b * NSEG + s] = (s < total) ? 1.0f : 0.0f;
}

// ---------------------------------------------------------------------------
// Pool accumulate: 16-token chunks, thread = 4 d over the chunk, atomic flush
// per segment run. Grid (128,8) = 1024 blocks x 256 threads.
// ---------------------------------------------------------------------------
__global__ __launch_bounds__(256) void pool_accum_kernel(
        const float* __restrict__ hidden, const int* __restrict__ segid,
        float* __restrict__ pooled) {
    const int chunk = blockIdx.x, b = blockIdx.y;
    const int tid = threadIdx.x;
    const int d0 = tid * 4;
    const int lbase = chunk * 16;
    const float* hb = hidden + (size_t)b * L_SZ * D_SZ + d0;
    const int* sg = segid + b * L_SZ + lbase;
    float4 acc = make_float4(0.f, 0.f, 0.f, 0.f);
    int cur = -1;
    #pragma unroll
    for (int t = 0; t < 16; ++t) {
        int sid = sg[t];
        if (sid != cur) {
            if (cur >= 0) {
                float* dst = pooled + ((size_t)(b * NSEG + cur)) * D_SZ + d0;
                atomicAdd(dst + 0, acc.x); atomicAdd(dst + 1, acc.y);
                atomicAdd(dst + 2, acc.z); atomicAdd(dst + 3, acc.w);
            }
            acc = make_float4(0.f, 0.f, 0.f, 0.f);
            cur = sid;
        }
        if (sid >= 0) {
            float4 v = *(const float4*)(hb + (size_t)(lbase + t) * D_SZ);
            acc.x += v.x; acc.y += v.y; acc.z += v.z; acc.w += v.w;
        }
    }
    if (cur >= 0) {
        float* dst = pooled + ((size_t)(b * NSEG + cur)) * D_SZ + d0;
        atomicAdd(dst + 0, acc.x); atomicAdd(dst + 1, acc.y);
        atomicAdd(dst + 2, acc.z); atomicAdd(dst + 3, acc.w);
    }
}

// ---------------------------------------------------------------------------
// Pool finalize: divide by count, add sinusoidal PE.
// ---------------------------------------------------------------------------
__global__ __launch_bounds__(256) void pool_final_kernel(
        float* __restrict__ pooled, const int* __restrict__ segstart) {
    const int s = blockIdx.x, b = blockIdx.y, tid = threadIdx.x;
    const int l0 = segstart[b * (NSEG + 1) + s];
    const int l1 = segstart[b * (NSEG + 1) + s + 1];
    const float inv = 1.0f / ((float)(l1 - l0) + 1e-9f);
    const int d0 = tid * 4;
    size_t o = ((size_t)(b * NSEG + s)) * D_SZ + d0;
    float4 v = *(float4*)(pooled + o);
    const float ce = -9.210340371976184f / 512.0f;
    const int i = d0 >> 1;
    const float a0 = (float)s * expf(ce * (float)i);
    const float a1 = (float)s * expf(ce * (float)(i + 1));
    float4 out;
    out.x = v.x * inv + sinf(a0);
    out.y = v.y * inv + cosf(a0);
    out.z = v.z * inv + sinf(a1);
    out.w = v.w * inv + cosf(a1);
    *(float4*)(pooled + o) = out;
}

// ---------------------------------------------------------------------------
extern "C" void kernel_launch(void* const* d_in, const int* in_sizes, int n_in,
                              void* d_out, int out_size, void* d_ws, size_t ws_size,
                              hipStream_t stream) {
    const float* hidden = (const float*)d_in[0];
    const float* amask  = (const float*)d_in[1];
    const float* w1     = (const float*)d_in[2];
    const float* b1     = (const float*)d_in[3];
    const float* w2     = (const float*)d_in[4];
    const float* b2     = (const float*)d_in[5];

    float* out    = (float*)d_out;
    float* pooled = out;
    float* nb     = out + POOLED_N;
    float* tp     = nb + 1;
    float* smask  = out + POOLED_N + 2;

    // zero pooled + scalars (short_mask fully overwritten by scan)
    hipMemsetAsync(d_out, 0, (size_t)(POOLED_N + 2) * sizeof(float), stream);

    const size_t HID_E = (size_t)B_SZ * L_SZ * D_SZ;           // 16,777,216
    const size_t OFF_HID16    = 0;
    const size_t OFF_BPACK    = OFF_HID16 + HID_E * 2;                 // 32 MB
    const size_t OFF_LOGITS   = OFF_BPACK + (size_t)CP * KDIM * 2;     // +2.25 MB
    const size_t OFF_SEGSTART = OFF_LOGITS + (size_t)B_SZ * LCONV * 4;
    const size_t OFF_SEGID    = OFF_SEGSTART + (size_t)B_SZ * (NSEG + 1) * 4;

    _Float16* hid16  = (_Float16*)((char*)d_ws + OFF_HID16);
    _Float16* bfrag  = (_Float16*)((char*)d_ws + OFF_BPACK);
    float*    logits = (float*)((char*)d_ws + OFF_LOGITS);
    int*      segst  = (int*)((char*)d_ws + OFF_SEGSTART);
    int*      segid  = (int*)((char*)d_ws + OFF_SEGID);

    convert_hidden_kernel<<<(int)(HID_E / 8 / 256), 256, 0, stream>>>(hidden, hid16);
    convert_w1_kernel<<<(CP * KDIM) / 256, 256, 0, stream>>>(w1, b2, bfrag, logits);
    conv_mfma_kernel<<<dim3(2, 32, B_SZ), 256, 0, stream>>>(hid16, bfrag, b1, w2, logits);
    fixup_kernel<<<dim3(32, B_SZ), 256, 0, stream>>>(hidden, w1, b1, w2, b2, logits);
    boundary_scan_kernel<<<B_SZ, 256, 0, stream>>>(logits, amask, segst, segid, nb, tp, smask);
    pool_accum_kernel<<<dim3(128, B_SZ), 256, 0, stream>>>(hidden, segid, pooled);
    pool_final_kernel<<<dim3(NSEG, B_SZ), 256, 0, stream>>>(pooled, segst);
}